// Round 18
// baseline (502.423 us; speedup 1.0000x reference)
//
#include <hip/hip_runtime.h>
#include <hip/hip_bf16.h>
#include <cmath>

// ---------------------------------------------------------------------------
// FourierNet fused forward, MI355X / gfx950.
// Round 18: wave-tile transpose on R15 (330us best; R17's deferred
// reductions reverted -- +12 regs respilled). 8 waves = 4 H-halves(64H) x
// 2 pt-halves(32pt) instead of 8x(32H x 64pt): LDS a-frag traffic HALVES
// (2 reads/ks vs 4; each f/h/t byte read by 4 waves not 8) at the cost of
// 2x weight reads (L2-resident, cheap). Guard: WRITE_SIZE <= 45MB (spill
// cliff at the 64-arch granule; wb[2][4]=+16 regs vs R15).
// Numerics identical (absmax 0.03125).
// ---------------------------------------------------------------------------

#define NSC   4
#define NFREQ 64
#define HID   256
#define NBLK  2
#define INF   514
#define TM    64
#define NTHR  512

// LDS: f arena 64 x 1024B swizzled; h 0..32K, t 32K..64K alias it
#define T_OFF    32768
#define SMEM_BYTES 65536

// d_ws packed-weight layout (bf16 elems): tiles of [kstep][256 rows][32 k]
#define TILE_E   8192
#define PROJ_OFF(s)    ((s) * 131072)
#define W1_OFF   524288
#define W2_OFF   1048576
#define WSB_ELEMS 1572864

static constexpr float S_IN = 0.04411042041035620f;  // 1/sqrt(514)
static constexpr float S_H  = 0.0625f;               // 1/sqrt(256)
static constexpr float LOG2E = 1.4426950408889634f;

typedef __attribute__((ext_vector_type(8))) short bf16x8;
typedef __attribute__((ext_vector_type(4))) float f32x4;

__device__ __forceinline__ unsigned short f2bf(float v) {
  __hip_bfloat16 b = __float2bfloat16(v);   // RNE
  unsigned short u;
  __builtin_memcpy(&u, &b, 2);
  return u;
}

__device__ __forceinline__ unsigned pack2(float a, float b) {
  return (unsigned)f2bf(a) | ((unsigned)f2bf(b) << 16);
}

// gelu(x) = 0.5 x (1 + erf(x/sqrt2)), erf via Abramowitz-Stegun 7.1.26
// (|eps| <= 1.5e-7, branch-free).
__device__ __forceinline__ float geluf(float x) {
  const float z = fabsf(x) * 0.7071067811865476f;
  const float t = __builtin_amdgcn_rcpf(fmaf(0.3275911f, z, 1.0f));
  float p = 1.061405429f;
  p = fmaf(p, t, -1.453152027f);
  p = fmaf(p, t, 1.421413741f);
  p = fmaf(p, t, -0.284496736f);
  p = fmaf(p, t, 0.254829592f);
  const float e = __builtin_amdgcn_exp2f(-z * z * LOG2E);
  const float erf_ = 1.0f - p * t * e;
  return 0.5f * x * (1.0f + copysignf(erf_, x));
}

// ---------------------------------------------------------------------------
// GEMM over KSTEPS K-steps. A from swizzled LDS, W from global (packed).
//   W frag: row = hq*64 + hf*16 + (lane&15), k = ks*32 + 8*(lane>>4)
//   A frag: pt  = ph*32 + pf*16 + (lane&15), same k; slot16 swizzled:
//           slot' = (ks*4+q) ^ (pt&7) within a ROWB-byte row.
//   D: pt-col = lane&15, H-row = hq*64+hf*16+4*(lane>>4)+r   [m89]
// wb[2][4] double-buffer prefetch; A frags consumed immediately (2/ks).
// ---------------------------------------------------------------------------
template<bool WS, bool PERM, int KSTEPS, int ROWB>
__device__ __forceinline__ void gemmK(const char* a_base,
                                      const unsigned short* __restrict__ wt,
                                      const float* __restrict__ wf,
                                      const int fp_rs, const int fp_co,
                                      const int lane, const int hq, const int ph,
                                      f32x4 acc[4][2]) {
  const int ar = lane & 15;
  const int q  = lane >> 4;
  bf16x8 wb[2][4];

  auto loadw = [&](int ks, bf16x8 w[4]) {
#pragma unroll
    for (int hf = 0; hf < 4; ++hf) {
      const int row = hq * 64 + hf * 16 + ar;
      if constexpr (WS) {
        w[hf] = *(const bf16x8*)(wt + ks * TILE_E + row * 32 + q * 8);
      } else if constexpr (PERM) {
        const int j = ks * 4 + q;
        const float* p = wf + row * fp_rs + fp_co;
#pragma unroll
        for (int e = 0; e < 8; ++e) w[hf][e] = (short)f2bf(p[e * 64 + j]);
      } else {
        const float* p = wf + row * fp_rs + fp_co + ks * 32 + q * 8;
#pragma unroll
        for (int e = 0; e < 8; ++e) w[hf][e] = (short)f2bf(p[e]);
      }
    }
  };

  loadw(0, wb[0]);
#pragma unroll
  for (int ks = 0; ks < KSTEPS; ++ks) {
    if (ks + 1 < KSTEPS) loadw(ks + 1, wb[(ks + 1) & 1]);
    __builtin_amdgcn_s_setprio(1);
#pragma unroll
    for (int pf = 0; pf < 2; ++pf) {
      const int pt = ph * 32 + pf * 16 + ar;
      const int slot = (ks * 4 + q) ^ (pt & 7);
      const bf16x8 a = *(const bf16x8*)(a_base + pt * ROWB + (slot << 4));
#pragma unroll
      for (int hf = 0; hf < 4; ++hf)
        acc[hf][pf] = __builtin_amdgcn_mfma_f32_16x16x32_bf16(wb[ks & 1][hf], a,
                                                              acc[hf][pf], 0, 0, 0);
    }
    __builtin_amdgcn_s_setprio(0);
  }
}

// Weight pre-pack (verified R4-R17): [kstep][256][32] tiles, proj columns
// permuted k' = j*8+g (source col = 2 + g*64 + j).
__global__ void cvt_weights(const float* __restrict__ projW,
                            const float* __restrict__ w1,
                            const float* __restrict__ w2,
                            unsigned short* __restrict__ o) {
  const int tot = WSB_ELEMS;
  for (int i = blockIdx.x * blockDim.x + threadIdx.x; i < tot;
       i += gridDim.x * blockDim.x) {
    float v;
    if (i < W1_OFF) {
      const int s = i >> 17, r = i & 131071;
      const int kst = r >> 13, rr = r & 8191;
      const int h = rr >> 5, kw = rr & 31;
      const int kp = kst * 32 + kw;
      const int j = kp >> 3, g = kp & 7;
      v = projW[(s * HID + h) * INF + 2 + g * 64 + j];
    } else if (i < W2_OFF) {
      const int i2 = i - W1_OFF;
      const int w = i2 >> 16, r = i2 & 65535;
      const int kst = r >> 13, h = (r >> 5) & 255, kw = r & 31;
      v = w1[w * 65536 + h * HID + kst * 32 + kw];
    } else {
      const int i2 = i - W2_OFF;
      const int w = i2 >> 16, r = i2 & 65535;
      const int kst = r >> 13, h = (r >> 5) & 255, kw = r & 31;
      v = w2[w * 65536 + h * HID + kst * 32 + kw];
    }
    o[i] = f2bf(v);
  }
}

template<bool WS>
__global__ __launch_bounds__(NTHR, 4)
void fnet_fused(const float* __restrict__ xy,
                const float* __restrict__ w_x,
                const float* __restrict__ w_y,
                const float* __restrict__ proj_W,
                const float* __restrict__ proj_b,
                const float* __restrict__ blk_W1,
                const float* __restrict__ blk_b1,
                const float* __restrict__ blk_W2,
                const float* __restrict__ blk_b2,
                const float* __restrict__ head_W,
                const float* __restrict__ head_b,
                const float* __restrict__ sc_W,
                const unsigned short* __restrict__ wsb,
                float* __restrict__ out) {
  extern __shared__ char smem[];
  char* f_arena = smem;                  // 64 x 1024B swizzled (K=512 bf16)
  char* h_base  = smem;                  // 64 x 512B swizzled (0..32K)
  char* t_base  = smem + T_OFF;          // 64 x 512B swizzled (32K..64K)

  const int tid  = threadIdx.x;
  const int lane = tid & 63;
  const int wave = tid >> 6;           // 0..7
  const int hq   = wave >> 1;          // H quarter (64 H)
  const int ph   = wave & 1;           // pt half (32 pts)
  const int m0   = blockIdx.x * TM;
  const int ar   = lane & 15;
  const int q    = lane >> 4;
  const float hb0 = head_b[0];

  // swizzled h/t tile address for this lane's (hf,pf) uint2 cell
  auto tile_addr = [&](char* base, int hf, int pf) -> char* {
    const int pt = ph * 32 + pf * 16 + ar;
    const int slot = (hq * 8 + hf * 2 + (q >> 1)) ^ (pt & 7);
    return base + pt * 512 + (slot << 4) + (q & 1) * 8;
  };

  f32x4 acc[4][2];   // single accumulator, reused by all GEMMs
  auto zacc = [&]() {
#pragma unroll
    for (int a_ = 0; a_ < 4; ++a_)
#pragma unroll
      for (int b_ = 0; b_ < 2; ++b_) acc[a_][b_] = (f32x4)0.f;
  };

  for (int s = 0; s < NSC; ++s) {
    // ---- fourier features -> f arena; shortcut dot -> global atomics ----
    // wave owns 8 pts; lane = freq j (0..63)
    {
      const int fj = lane;
      const float bx = __builtin_amdgcn_exp2f(w_x[s * NFREQ + fj] * LOG2E);
      const float by = __builtin_amdgcn_exp2f(w_y[s * NFREQ + fj] * LOG2E);
      float sc8[8];
#pragma unroll
      for (int g2 = 0; g2 < 8; ++g2) sc8[g2] = sc_W[s * INF + 2 + g2 * NFREQ + fj];
      const float scW0 = sc_W[s * INF], scW1 = sc_W[s * INF + 1];
#pragma unroll 2
      for (int p = 0; p < 8; ++p) {
        const int pt = wave * 8 + p;
        const float x  = xy[(m0 + pt) * 2];
        const float yv = xy[(m0 + pt) * 2 + 1];
        // angle pi*x*B == 2*pi*t revolutions; v_sin/v_cos take revolutions
        float tx = 0.5f * x * bx;  tx -= floorf(tx);
        float ty = 0.5f * yv * by; ty -= floorf(ty);
        const float sx = __builtin_amdgcn_sinf(tx);
        const float cx = __builtin_amdgcn_cosf(tx);
        const float sy = __builtin_amdgcn_sinf(ty);
        const float cy = __builtin_amdgcn_cosf(ty);
        const float p1 = sx * cy, p2 = cx * sy, p3 = cx * cy, p4 = sx * sy;
        const float g0 = sx, g1 = cx, g2 = sy, g3 = cy;
        const float g4 = p1 + p2, g5 = p3 - p4, g6 = p1 - p2, g7 = p3 + p4;
        uint4 wv;
        wv.x = pack2(g0, g1); wv.y = pack2(g2, g3);
        wv.z = pack2(g4, g5); wv.w = pack2(g6, g7);
        *(uint4*)(f_arena + pt * 1024 + ((fj ^ (pt & 7)) << 4)) = wv;
        float psum = g0 * sc8[0] + g1 * sc8[1] + g2 * sc8[2] + g3 * sc8[3]
                   + g4 * sc8[4] + g5 * sc8[5] + g6 * sc8[6] + g7 * sc8[7];
        psum += __shfl_xor(psum, 1, 64);
        psum += __shfl_xor(psum, 2, 64);
        psum += __shfl_xor(psum, 4, 64);
        psum += __shfl_xor(psum, 8, 64);
        psum += __shfl_xor(psum, 16, 64);
        psum += __shfl_xor(psum, 32, 64);
        if (lane == 0)
          atomicAdd(&out[m0 + pt],
                    psum + x * scW0 + yv * scW1 + (s == 0 ? hb0 : 0.f));
      }
    }
    __syncthreads();

    // ---- proj GEMM (K=512): h = gelu((f@W^T + x*w0 + y*w1)*s_in + b) ----
    zacc();
    gemmK<WS, true, 16, 1024>(f_arena, wsb + PROJ_OFF(s),
                              proj_W + s * HID * INF, INF, 2,
                              lane, hq, ph, acc);
    __syncthreads();   // all waves done reading f arena

    // epilogue streamed hf-by-hf, straight to LDS h tile
#pragma unroll
    for (int hf = 0; hf < 4; ++hf) {
      const int Hb = hq * 64 + hf * 16 + 4 * q;
      const float4 pb4 = *(const float4*)(proj_b + s * HID + Hb);
      const float pbv[4] = {pb4.x, pb4.y, pb4.z, pb4.w};
      float wx0[4], wy0[4];
#pragma unroll
      for (int r = 0; r < 4; ++r) {
        const float2 w01 = *(const float2*)(proj_W + (size_t)(s * HID + Hb + r) * INF);
        wx0[r] = w01.x; wy0[r] = w01.y;
      }
#pragma unroll
      for (int pf = 0; pf < 2; ++pf) {
        const int pt = ph * 32 + pf * 16 + ar;
        const float2 xp2 = *(const float2*)(xy + (m0 + pt) * 2);
        float hv[4];
#pragma unroll
        for (int r = 0; r < 4; ++r)
          hv[r] = geluf((acc[hf][pf][r] + xp2.x * wx0[r] + xp2.y * wy0[r]) * S_IN + pbv[r]);
        *(uint2*)tile_addr(h_base, hf, pf) =
            make_uint2(pack2(hv[0], hv[1]), pack2(hv[2], hv[3]));
      }
    }
    __syncthreads();

    // ---- residual blocks ----
    for (int b = 0; b < NBLK; ++b) {
      const int wb_ = s * NBLK + b;
      zacc();
      gemmK<WS, false, 8, 512>(h_base, wsb + W1_OFF + wb_ * 65536,
                               blk_W1 + wb_ * 65536, HID, 0,
                               lane, hq, ph, acc);
      // t = gelu(acc*s_h + b1) -> t tile (disjoint from h)
#pragma unroll
      for (int hf = 0; hf < 4; ++hf) {
        const int Hb = hq * 64 + hf * 16 + 4 * q;
        const float4 b14 = *(const float4*)(blk_b1 + wb_ * HID + Hb);
        const float b1v[4] = {b14.x, b14.y, b14.z, b14.w};
#pragma unroll
        for (int pf = 0; pf < 2; ++pf)
          *(uint2*)tile_addr(t_base, hf, pf) =
              make_uint2(pack2(geluf(acc[hf][pf][0] * S_H + b1v[0]),
                               geluf(acc[hf][pf][1] * S_H + b1v[1])),
                         pack2(geluf(acc[hf][pf][2] * S_H + b1v[2]),
                               geluf(acc[hf][pf][3] * S_H + b1v[3])));
      }
      __syncthreads();   // t complete; all GEMM1 h-reads done

      zacc();
      gemmK<WS, false, 8, 512>(t_base, wsb + W2_OFF + wb_ * 65536,
                               blk_W2 + wb_ * 65536, HID, 0,
                               lane, hq, ph, acc);

      if (b + 1 < NBLK) {
        // h' = h(LDS readback, own cells) + acc*s_h + b2 -> h tile
#pragma unroll
        for (int hf = 0; hf < 4; ++hf) {
          const int Hb = hq * 64 + hf * 16 + 4 * q;
          const float4 b24 = *(const float4*)(blk_b2 + wb_ * HID + Hb);
          const float b2v[4] = {b24.x, b24.y, b24.z, b24.w};
#pragma unroll
          for (int pf = 0; pf < 2; ++pf) {
            const uint2 u = *(const uint2*)tile_addr(h_base, hf, pf);
            float hv[4];
            hv[0] = __uint_as_float(u.x << 16)         + acc[hf][pf][0] * S_H + b2v[0];
            hv[1] = __uint_as_float(u.x & 0xffff0000u) + acc[hf][pf][1] * S_H + b2v[1];
            hv[2] = __uint_as_float(u.y << 16)         + acc[hf][pf][2] * S_H + b2v[2];
            hv[3] = __uint_as_float(u.y & 0xffff0000u) + acc[hf][pf][3] * S_H + b2v[3];
            *(uint2*)tile_addr(h_base, hf, pf) =
                make_uint2(pack2(hv[0], hv[1]), pack2(hv[2], hv[3]));
          }
        }
      } else {
        // final head partial: hf-outer so b2/head_W load once per hf
        float v[2] = {0.f, 0.f};
#pragma unroll
        for (int hf = 0; hf < 4; ++hf) {
          const int Hb = hq * 64 + hf * 16 + 4 * q;
          const float4 b24 = *(const float4*)(blk_b2 + wb_ * HID + Hb);
          const float4 hw4 = *(const float4*)(head_W + Hb);
#pragma unroll
          for (int pf = 0; pf < 2; ++pf) {
            const uint2 u = *(const uint2*)tile_addr(h_base, hf, pf);
            v[pf] += (__uint_as_float(u.x << 16)         + acc[hf][pf][0] * S_H + b24.x) * hw4.x
                   + (__uint_as_float(u.x & 0xffff0000u) + acc[hf][pf][1] * S_H + b24.y) * hw4.y
                   + (__uint_as_float(u.y << 16)         + acc[hf][pf][2] * S_H + b24.z) * hw4.z
                   + (__uint_as_float(u.y & 0xffff0000u) + acc[hf][pf][3] * S_H + b24.w) * hw4.w;
          }
        }
#pragma unroll
        for (int pf = 0; pf < 2; ++pf) {
          float vv = v[pf];
          vv += __shfl_xor(vv, 16, 64);
          vv += __shfl_xor(vv, 32, 64);
          if (lane < 16) atomicAdd(&out[m0 + ph * 32 + pf * 16 + ar], vv);
        }
      }
      __syncthreads();
    }
  }
}

extern "C" void kernel_launch(void* const* d_in, const int* in_sizes, int n_in,
                              void* d_out, int out_size, void* d_ws, size_t ws_size,
                              hipStream_t stream) {
  (void)in_sizes; (void)n_in;
  const float* xy     = (const float*)d_in[0];
  const float* w_x    = (const float*)d_in[1];
  const float* w_y    = (const float*)d_in[2];
  const float* proj_W = (const float*)d_in[3];
  const float* proj_b = (const float*)d_in[4];
  const float* blk_W1 = (const float*)d_in[5];
  const float* blk_b1 = (const float*)d_in[6];
  const float* blk_W2 = (const float*)d_in[7];
  const float* blk_b2 = (const float*)d_in[8];
  const float* head_W = (const float*)d_in[9];
  const float* head_b = (const float*)d_in[10];
  const float* sc_W   = (const float*)d_in[11];
  float* out = (float*)d_out;

  const bool use_ws = ws_size >= (size_t)WSB_ELEMS * 2;
  const int nblocks = out_size / TM;   // 65536/64 = 1024

  (void)hipMemsetAsync(d_out, 0, (size_t)out_size * sizeof(float), stream);

  if (use_ws) {
    cvt_weights<<<768, 256, 0, stream>>>(proj_W, blk_W1, blk_W2,
                                         (unsigned short*)d_ws);
    fnet_fused<true><<<nblocks, NTHR, SMEM_BYTES, stream>>>(
        xy, w_x, w_y, proj_W, proj_b, blk_W1, blk_b1, blk_W2, blk_b2,
        head_W, head_b, sc_W, (const unsigned short*)d_ws, out);
  } else {
    fnet_fused<false><<<nblocks, NTHR, SMEM_BYTES, stream>>>(
        xy, w_x, w_y, proj_W, proj_b, blk_W1, blk_b1, blk_W2, blk_b2,
        head_W, head_b, sc_W, (const unsigned short*)nullptr, out);
  }
}

// Round 19
// 399.423 us; speedup vs baseline: 1.2579x; 1.2579x over previous
//
#include <hip/hip_runtime.h>
#include <hip/hip_bf16.h>
#include <cmath>

// ---------------------------------------------------------------------------
// FourierNet fused forward, MI355X / gfx950.
// Round 19: 32x32x16 MFMA rewrite of the R15 structure (330us best).
// R16-R18 proved the 16x16 structure has ZERO register slack (every add
// spills at the 64-arch granule). 32x32x16 REDUCES pressure:
//   per K-step-16: 1 wfrag (4 regs, wb[2]=8) + 2 afrags (immediate) +
//   2 MFMA (vs 4 wfrags/8 MFMA for 16x16). acc = 2 x f32x16 = 32 AGPR.
//   Arch estimate ~55 < 64 granule -> slack at last.
// MFMA instrs /4 at 15% higher pipe rate (2382 vs 2075 TF); LDS B/FLOP /2.
// Layouts: D col=lane&31, row=(reg&3)+8*(reg>>2)+4*(lane>>5) [m74/m101];
// A/B row|col=lane&31, k=(lane>>5)*8+e (m89 pattern). Weights repacked to
// [kstep16][256][16] tiles, proj k' = j*8+g preserved (fourier unchanged).
// Skeleton (TM=64, 512thr, 8 waves x (32H x 64pt), 2 blk/CU, barriers,
// fourier, shortcut, h/t swizzle) identical to R15. absmax ~0.031.
// ---------------------------------------------------------------------------

#define NSC   4
#define NFREQ 64
#define HID   256
#define NBLK  2
#define INF   514
#define TM    64
#define NTHR  512

// LDS: f arena 64 x 1024B swizzled; h 0..32K, t 32K..64K alias it
#define T_OFF    32768
#define SMEM_BYTES 65536

// d_ws packed-weight layout (bf16 elems): tiles of [kstep16][256 rows][16 k]
#define TILE_E   4096
#define PROJ_OFF(s)    ((s) * 131072)
#define W1_OFF   524288
#define W2_OFF   1048576
#define WSB_ELEMS 1572864

static constexpr float S_IN = 0.04411042041035620f;  // 1/sqrt(514)
static constexpr float S_H  = 0.0625f;               // 1/sqrt(256)
static constexpr float LOG2E = 1.4426950408889634f;

typedef __attribute__((ext_vector_type(8)))  short bf16x8;
typedef __attribute__((ext_vector_type(16))) float f32x16;

__device__ __forceinline__ unsigned short f2bf(float v) {
  __hip_bfloat16 b = __float2bfloat16(v);   // RNE
  unsigned short u;
  __builtin_memcpy(&u, &b, 2);
  return u;
}

__device__ __forceinline__ unsigned pack2(float a, float b) {
  return (unsigned)f2bf(a) | ((unsigned)f2bf(b) << 16);
}

// gelu(x) = 0.5 x (1 + erf(x/sqrt2)), erf via Abramowitz-Stegun 7.1.26
// (|eps| <= 1.5e-7, branch-free).
__device__ __forceinline__ float geluf(float x) {
  const float z = fabsf(x) * 0.7071067811865476f;
  const float t = __builtin_amdgcn_rcpf(fmaf(0.3275911f, z, 1.0f));
  float p = 1.061405429f;
  p = fmaf(p, t, -1.453152027f);
  p = fmaf(p, t, 1.421413741f);
  p = fmaf(p, t, -0.284496736f);
  p = fmaf(p, t, 0.254829592f);
  const float e = __builtin_amdgcn_exp2f(-z * z * LOG2E);
  const float erf_ = 1.0f - p * t * e;
  return 0.5f * x * (1.0f + copysignf(erf_, x));
}

// ---------------------------------------------------------------------------
// 32x32x16 GEMM over KS16 K-steps (K = KS16*16). A from swizzled LDS,
// W from global (packed [ks][256][16] tiles).
//   W frag (A-op): row = hq*32 + (lane&31), k = ks*16 + (lane>>5)*8 + e
//   A frag (B-op): pt  = pb*32 + (lane&31), same k; slot16 = ks*2+(lane>>5),
//                  swizzled ^ (pt&7) within a ROWB-byte row.
//   D: pt-col = lane&31, H-row = (reg&3)+8*(reg>>2)+4*(lane>>5)  [m74/m101]
// wb[2] double-buffer prefetch; A frags consumed immediately.
// ---------------------------------------------------------------------------
template<bool WS, bool PERM, int KS16, int ROWB>
__device__ __forceinline__ void gemm32(const char* a_base,
                                       const unsigned short* __restrict__ wt,
                                       const float* __restrict__ wf,
                                       const int fp_rs, const int fp_co,
                                       const int lane, const int hq,
                                       f32x16 acc[2]) {
  const int lr = lane & 31;
  const int kg = lane >> 5;
  bf16x8 wb[2];

  auto loadw = [&](int ks) -> bf16x8 {
    const int row = hq * 32 + lr;
    if constexpr (WS) {
      return *(const bf16x8*)(wt + ks * TILE_E + row * 16 + kg * 8);
    } else if constexpr (PERM) {
      const int j = ks * 2 + kg;
      const float* p = wf + row * fp_rs + fp_co;
      bf16x8 w;
#pragma unroll
      for (int e = 0; e < 8; ++e) w[e] = (short)f2bf(p[e * 64 + j]);
      return w;
    } else {
      const float* p = wf + row * fp_rs + fp_co + ks * 16 + kg * 8;
      bf16x8 w;
#pragma unroll
      for (int e = 0; e < 8; ++e) w[e] = (short)f2bf(p[e]);
      return w;
    }
  };

  wb[0] = loadw(0);
#pragma unroll
  for (int ks = 0; ks < KS16; ++ks) {
    if (ks + 1 < KS16) wb[(ks + 1) & 1] = loadw(ks + 1);
    const bf16x8 w = wb[ks & 1];
    __builtin_amdgcn_s_setprio(1);
#pragma unroll
    for (int pb = 0; pb < 2; ++pb) {
      const int pt = pb * 32 + lr;
      const int slot = (ks * 2 + kg) ^ (pt & 7);
      const bf16x8 a = *(const bf16x8*)(a_base + pt * ROWB + (slot << 4));
      acc[pb] = __builtin_amdgcn_mfma_f32_32x32x16_bf16(w, a, acc[pb], 0, 0, 0);
    }
    __builtin_amdgcn_s_setprio(0);
  }
}

// Weight pre-pack: [kstep16][256][16] tiles; proj columns permuted
// k' = j*8+g (source col = 2 + g*64 + j) -- fourier layout unchanged.
__global__ void cvt_weights(const float* __restrict__ projW,
                            const float* __restrict__ w1,
                            const float* __restrict__ w2,
                            unsigned short* __restrict__ o) {
  const int tot = WSB_ELEMS;
  for (int i = blockIdx.x * blockDim.x + threadIdx.x; i < tot;
       i += gridDim.x * blockDim.x) {
    float v;
    if (i < W1_OFF) {
      const int s = i >> 17, r = i & 131071;
      const int kst = r >> 12, rr = r & 4095;
      const int h = rr >> 4, kw = rr & 15;
      const int kp = kst * 16 + kw;
      const int j = kp >> 3, g = kp & 7;
      v = projW[(s * HID + h) * INF + 2 + g * 64 + j];
    } else if (i < W2_OFF) {
      const int i2 = i - W1_OFF;
      const int w = i2 >> 16, r = i2 & 65535;
      const int kst = r >> 12, h = (r >> 4) & 255, kw = r & 15;
      v = w1[w * 65536 + h * HID + kst * 16 + kw];
    } else {
      const int i2 = i - W2_OFF;
      const int w = i2 >> 16, r = i2 & 65535;
      const int kst = r >> 12, h = (r >> 4) & 255, kw = r & 15;
      v = w2[w * 65536 + h * HID + kst * 16 + kw];
    }
    o[i] = f2bf(v);
  }
}

template<bool WS>
__global__ __launch_bounds__(NTHR, 4)
void fnet_fused(const float* __restrict__ xy,
                const float* __restrict__ w_x,
                const float* __restrict__ w_y,
                const float* __restrict__ proj_W,
                const float* __restrict__ proj_b,
                const float* __restrict__ blk_W1,
                const float* __restrict__ blk_b1,
                const float* __restrict__ blk_W2,
                const float* __restrict__ blk_b2,
                const float* __restrict__ head_W,
                const float* __restrict__ head_b,
                const float* __restrict__ sc_W,
                const unsigned short* __restrict__ wsb,
                float* __restrict__ out) {
  extern __shared__ char smem[];
  char* f_arena = smem;                  // 64 x 1024B swizzled (K=512 bf16)
  char* h_base  = smem;                  // 64 x 512B swizzled (0..32K)
  char* t_base  = smem + T_OFF;          // 64 x 512B swizzled (32K..64K)

  const int tid  = threadIdx.x;
  const int lane = tid & 63;
  const int wave = tid >> 6;           // 0..7
  const int hq   = wave;               // H octant (32 H)
  const int m0   = blockIdx.x * TM;
  const int lr   = lane & 31;
  const int kg   = lane >> 5;          // k-group / H-offset 4*kg
  const float hb0 = head_b[0];

  // swizzled h/t tile address for this lane's (pb,grp) uint2 cell
  // H = hq*32 + grp*8 + 4*kg + (0..3); byte = slot16*16 + kg*8,
  // slot16 = hq*4+grp, swizzled ^ (pt&7).
  auto tile_addr = [&](char* base, int pb, int grp) -> char* {
    const int pt = pb * 32 + lr;
    const int slot = (hq * 4 + grp) ^ (pt & 7);
    return base + pt * 512 + (slot << 4) + kg * 8;
  };

  f32x16 acc[2];   // 2 pt-blocks x 16 regs (32 AGPR), reused by all GEMMs
  auto zacc = [&]() {
    acc[0] = (f32x16)0.f;
    acc[1] = (f32x16)0.f;
  };

  for (int s = 0; s < NSC; ++s) {
    // ---- fourier features -> f arena; shortcut dot -> global atomics ----
    // wave owns 8 pts; lane = freq j (0..63)  [identical to R15]
    {
      const int fj = lane;
      const float bx = __builtin_amdgcn_exp2f(w_x[s * NFREQ + fj] * LOG2E);
      const float by = __builtin_amdgcn_exp2f(w_y[s * NFREQ + fj] * LOG2E);
      float sc8[8];
#pragma unroll
      for (int g2 = 0; g2 < 8; ++g2) sc8[g2] = sc_W[s * INF + 2 + g2 * NFREQ + fj];
      const float scW0 = sc_W[s * INF], scW1 = sc_W[s * INF + 1];
#pragma unroll 2
      for (int p = 0; p < 8; ++p) {
        const int pt = wave * 8 + p;
        const float x  = xy[(m0 + pt) * 2];
        const float yv = xy[(m0 + pt) * 2 + 1];
        // angle pi*x*B == 2*pi*t revolutions; v_sin/v_cos take revolutions
        float tx = 0.5f * x * bx;  tx -= floorf(tx);
        float ty = 0.5f * yv * by; ty -= floorf(ty);
        const float sx = __builtin_amdgcn_sinf(tx);
        const float cx = __builtin_amdgcn_cosf(tx);
        const float sy = __builtin_amdgcn_sinf(ty);
        const float cy = __builtin_amdgcn_cosf(ty);
        const float p1 = sx * cy, p2 = cx * sy, p3 = cx * cy, p4 = sx * sy;
        const float g0 = sx, g1 = cx, g2 = sy, g3 = cy;
        const float g4 = p1 + p2, g5 = p3 - p4, g6 = p1 - p2, g7 = p3 + p4;
        uint4 wv;
        wv.x = pack2(g0, g1); wv.y = pack2(g2, g3);
        wv.z = pack2(g4, g5); wv.w = pack2(g6, g7);
        *(uint4*)(f_arena + pt * 1024 + ((fj ^ (pt & 7)) << 4)) = wv;
        float psum = g0 * sc8[0] + g1 * sc8[1] + g2 * sc8[2] + g3 * sc8[3]
                   + g4 * sc8[4] + g5 * sc8[5] + g6 * sc8[6] + g7 * sc8[7];
        psum += __shfl_xor(psum, 1, 64);
        psum += __shfl_xor(psum, 2, 64);
        psum += __shfl_xor(psum, 4, 64);
        psum += __shfl_xor(psum, 8, 64);
        psum += __shfl_xor(psum, 16, 64);
        psum += __shfl_xor(psum, 32, 64);
        if (lane == 0)
          atomicAdd(&out[m0 + pt],
                    psum + x * scW0 + yv * scW1 + (s == 0 ? hb0 : 0.f));
      }
    }
    __syncthreads();

    // ---- proj GEMM (K=512): h = gelu((f@W^T + x*w0 + y*w1)*s_in + b) ----
    zacc();
    gemm32<WS, true, 32, 1024>(f_arena, wsb + PROJ_OFF(s),
                               proj_W + s * HID * INF, INF, 2,
                               lane, hq, acc);
    __syncthreads();   // all waves done reading f arena

    // epilogue: per lane 2 pts x 16 H (4 groups of 4 consecutive H)
#pragma unroll
    for (int grp = 0; grp < 4; ++grp) {
      const int Hb = hq * 32 + grp * 8 + 4 * kg;
      const float4 pb4 = *(const float4*)(proj_b + s * HID + Hb);
      const float pbv[4] = {pb4.x, pb4.y, pb4.z, pb4.w};
      float wx0[4], wy0[4];
#pragma unroll
      for (int r = 0; r < 4; ++r) {
        const float2 w01 = *(const float2*)(proj_W + (size_t)(s * HID + Hb + r) * INF);
        wx0[r] = w01.x; wy0[r] = w01.y;
      }
#pragma unroll
      for (int pb = 0; pb < 2; ++pb) {
        const int pt = pb * 32 + lr;
        const float2 xp2 = *(const float2*)(xy + (m0 + pt) * 2);
        float hv[4];
#pragma unroll
        for (int r = 0; r < 4; ++r)
          hv[r] = geluf((acc[pb][grp * 4 + r] + xp2.x * wx0[r] + xp2.y * wy0[r])
                            * S_IN + pbv[r]);
        *(uint2*)tile_addr(h_base, pb, grp) =
            make_uint2(pack2(hv[0], hv[1]), pack2(hv[2], hv[3]));
      }
    }
    __syncthreads();

    // ---- residual blocks ----
    for (int b = 0; b < NBLK; ++b) {
      const int wb_ = s * NBLK + b;
      zacc();
      gemm32<WS, false, 16, 512>(h_base, wsb + W1_OFF + wb_ * 65536,
                                 blk_W1 + wb_ * 65536, HID, 0,
                                 lane, hq, acc);
      // t = gelu(acc*s_h + b1) -> t tile (disjoint from h)
#pragma unroll
      for (int grp = 0; grp < 4; ++grp) {
        const int Hb = hq * 32 + grp * 8 + 4 * kg;
        const float4 b14 = *(const float4*)(blk_b1 + wb_ * HID + Hb);
        const float b1v[4] = {b14.x, b14.y, b14.z, b14.w};
#pragma unroll
        for (int pb = 0; pb < 2; ++pb)
          *(uint2*)tile_addr(t_base, pb, grp) =
              make_uint2(pack2(geluf(acc[pb][grp * 4 + 0] * S_H + b1v[0]),
                               geluf(acc[pb][grp * 4 + 1] * S_H + b1v[1])),
                         pack2(geluf(acc[pb][grp * 4 + 2] * S_H + b1v[2]),
                               geluf(acc[pb][grp * 4 + 3] * S_H + b1v[3])));
      }
      __syncthreads();   // t complete; all GEMM1 h-reads done

      zacc();
      gemm32<WS, false, 16, 512>(t_base, wsb + W2_OFF + wb_ * 65536,
                                 blk_W2 + wb_ * 65536, HID, 0,
                                 lane, hq, acc);

      if (b + 1 < NBLK) {
        // h' = h(LDS readback, own cells) + acc*s_h + b2 -> h tile
#pragma unroll
        for (int grp = 0; grp < 4; ++grp) {
          const int Hb = hq * 32 + grp * 8 + 4 * kg;
          const float4 b24 = *(const float4*)(blk_b2 + wb_ * HID + Hb);
          const float b2v[4] = {b24.x, b24.y, b24.z, b24.w};
#pragma unroll
          for (int pb = 0; pb < 2; ++pb) {
            const uint2 u = *(const uint2*)tile_addr(h_base, pb, grp);
            float hv[4];
            hv[0] = __uint_as_float(u.x << 16)         + acc[pb][grp * 4 + 0] * S_H + b2v[0];
            hv[1] = __uint_as_float(u.x & 0xffff0000u) + acc[pb][grp * 4 + 1] * S_H + b2v[1];
            hv[2] = __uint_as_float(u.y << 16)         + acc[pb][grp * 4 + 2] * S_H + b2v[2];
            hv[3] = __uint_as_float(u.y & 0xffff0000u) + acc[pb][grp * 4 + 3] * S_H + b2v[3];
            *(uint2*)tile_addr(h_base, pb, grp) =
                make_uint2(pack2(hv[0], hv[1]), pack2(hv[2], hv[3]));
          }
        }
      } else {
        // final head partial: per lane 2 pts; reduce across kg (lane^32)
        float v[2] = {0.f, 0.f};
#pragma unroll
        for (int grp = 0; grp < 4; ++grp) {
          const int Hb = hq * 32 + grp * 8 + 4 * kg;
          const float4 b24 = *(const float4*)(blk_b2 + wb_ * HID + Hb);
          const float4 hw4 = *(const float4*)(head_W + Hb);
#pragma unroll
          for (int pb = 0; pb < 2; ++pb) {
            const uint2 u = *(const uint2*)tile_addr(h_base, pb, grp);
            v[pb] += (__uint_as_float(u.x << 16)         + acc[pb][grp * 4 + 0] * S_H + b24.x) * hw4.x
                   + (__uint_as_float(u.x & 0xffff0000u) + acc[pb][grp * 4 + 1] * S_H + b24.y) * hw4.y
                   + (__uint_as_float(u.y << 16)         + acc[pb][grp * 4 + 2] * S_H + b24.z) * hw4.z
                   + (__uint_as_float(u.y & 0xffff0000u) + acc[pb][grp * 4 + 3] * S_H + b24.w) * hw4.w;
          }
        }
#pragma unroll
        for (int pb = 0; pb < 2; ++pb) {
          float vv = v[pb];
          vv += __shfl_xor(vv, 32, 64);
          if (lane < 32) atomicAdd(&out[m0 + pb * 32 + lr], vv);
        }
      }
      __syncthreads();
    }
  }
}

extern "C" void kernel_launch(void* const* d_in, const int* in_sizes, int n_in,
                              void* d_out, int out_size, void* d_ws, size_t ws_size,
                              hipStream_t stream) {
  (void)in_sizes; (void)n_in;
  const float* xy     = (const float*)d_in[0];
  const float* w_x    = (const float*)d_in[1];
  const float* w_y    = (const float*)d_in[2];
  const float* proj_W = (const float*)d_in[3];
  const float* proj_b = (const float*)d_in[4];
  const float* blk_W1 = (const float*)d_in[5];
  const float* blk_b1 = (const float*)d_in[6];
  const float* blk_W2 = (const float*)d_in[7];
  const float* blk_b2 = (const float*)d_in[8];
  const float* head_W = (const float*)d_in[9];
  const float* head_b = (const float*)d_in[10];
  const float* sc_W   = (const float*)d_in[11];
  float* out = (float*)d_out;

  const bool use_ws = ws_size >= (size_t)WSB_ELEMS * 2;
  const int nblocks = out_size / TM;   // 65536/64 = 1024

  (void)hipMemsetAsync(d_out, 0, (size_t)out_size * sizeof(float), stream);

  if (use_ws) {
    cvt_weights<<<768, 256, 0, stream>>>(proj_W, blk_W1, blk_W2,
                                         (unsigned short*)d_ws);
    fnet_fused<true><<<nblocks, NTHR, SMEM_BYTES, stream>>>(
        xy, w_x, w_y, proj_W, proj_b, blk_W1, blk_b1, blk_W2, blk_b2,
        head_W, head_b, sc_W, (const unsigned short*)d_ws, out);
  } else {
    fnet_fused<false><<<nblocks, NTHR, SMEM_BYTES, stream>>>(
        xy, w_x, w_y, proj_W, proj_b, blk_W1, blk_b1, blk_W2, blk_b2,
        head_W, head_b, sc_W, (const unsigned short*)nullptr, out);
  }
}

// Round 20
// 330.059 us; speedup vs baseline: 1.5222x; 1.2102x over previous
//
#include <hip/hip_runtime.h>
#include <hip/hip_bf16.h>
#include <cmath>

// ---------------------------------------------------------------------------
// FourierNet fused forward, MI355X / gfx950.
// Round 20: REVERT to R15 (330us, session best). R16-R19 post-mortems proved
// the structure is register-boxed: 2 blocks/CU => 4 waves/SIMD => 128-reg
// budget => fixed 64-arch/64-acc split; every enhancement (3-buf prefetch,
// deferred reductions, transposed wave tile, 32x32 MFMA) pushed arch > 64
// and spilled (WRITE_SIZE 72-145MB), losing more than it gained. R15 is the
// measured optimum of this box: TM=64, 512thr, 8 waves x (32H x 64pt),
// 2 de-phased blocks/CU, packed bf16 weights, swizzled LDS, fast-erf gelu,
// immediate-consume A-frags. absmax 0.03125.
// ---------------------------------------------------------------------------

#define NSC   4
#define NFREQ 64
#define HID   256
#define NBLK  2
#define INF   514
#define TM    64
#define NTHR  512

// LDS: f arena 64 x 1024B swizzled; h 0..32K, t 32K..64K alias it
#define T_OFF    32768
#define SMEM_BYTES 65536

// d_ws packed-weight layout (bf16 elems): tiles of [kstep][256 rows][32 k]
#define TILE_E   8192
#define PROJ_OFF(s)    ((s) * 131072)
#define W1_OFF   524288
#define W2_OFF   1048576
#define WSB_ELEMS 1572864

static constexpr float S_IN = 0.04411042041035620f;  // 1/sqrt(514)
static constexpr float S_H  = 0.0625f;               // 1/sqrt(256)
static constexpr float LOG2E = 1.4426950408889634f;

typedef __attribute__((ext_vector_type(8))) short bf16x8;
typedef __attribute__((ext_vector_type(4))) float f32x4;

__device__ __forceinline__ unsigned short f2bf(float v) {
  __hip_bfloat16 b = __float2bfloat16(v);   // RNE
  unsigned short u;
  __builtin_memcpy(&u, &b, 2);
  return u;
}

__device__ __forceinline__ unsigned pack2(float a, float b) {
  return (unsigned)f2bf(a) | ((unsigned)f2bf(b) << 16);
}

// gelu(x) = 0.5 x (1 + erf(x/sqrt2)), erf via Abramowitz-Stegun 7.1.26
// (|eps| <= 1.5e-7, branch-free).
__device__ __forceinline__ float geluf(float x) {
  const float z = fabsf(x) * 0.7071067811865476f;
  const float t = __builtin_amdgcn_rcpf(fmaf(0.3275911f, z, 1.0f));
  float p = 1.061405429f;
  p = fmaf(p, t, -1.453152027f);
  p = fmaf(p, t, 1.421413741f);
  p = fmaf(p, t, -0.284496736f);
  p = fmaf(p, t, 0.254829592f);
  const float e = __builtin_amdgcn_exp2f(-z * z * LOG2E);
  const float erf_ = 1.0f - p * t * e;
  return 0.5f * x * (1.0f + copysignf(erf_, x));
}

// ---------------------------------------------------------------------------
// GEMM over KSTEPS K-steps. A from swizzled LDS, W from global (packed).
//   W frag: row = hq*32 + hf*16 + (lane&15), k = ks*32 + 8*(lane>>4)
//   A frag: pt  = pf*16 + (lane&15), same k; slot16 swizzled:
//           slot' = (ks*4+q) ^ (pt&7) within a ROWB-byte row.
//   D: pt-col = lane&15, H-row = hq*32+hf*16+4*(lane>>4)+r   [m89]
// wb double-buffer prefetch; A fragments consumed immediately (live = 4
// regs) to keep peak arch pressure under the 64-reg granule.
// ---------------------------------------------------------------------------
template<bool WS, bool PERM, int KSTEPS, int ROWB>
__device__ __forceinline__ void gemmK(const char* a_base,
                                      const unsigned short* __restrict__ wt,
                                      const float* __restrict__ wf,
                                      const int fp_rs, const int fp_co,
                                      const int lane, const int hq,
                                      f32x4 acc[2][4]) {
  const int ar = lane & 15;
  const int q  = lane >> 4;
  bf16x8 wb[2][2];

  auto loadw = [&](int ks, bf16x8 w[2]) {
#pragma unroll
    for (int hf = 0; hf < 2; ++hf) {
      const int row = hq * 32 + hf * 16 + ar;
      if constexpr (WS) {
        w[hf] = *(const bf16x8*)(wt + ks * TILE_E + row * 32 + q * 8);
      } else if constexpr (PERM) {
        const int j = ks * 4 + q;
        const float* p = wf + row * fp_rs + fp_co;
#pragma unroll
        for (int e = 0; e < 8; ++e) w[hf][e] = (short)f2bf(p[e * 64 + j]);
      } else {
        const float* p = wf + row * fp_rs + fp_co + ks * 32 + q * 8;
#pragma unroll
        for (int e = 0; e < 8; ++e) w[hf][e] = (short)f2bf(p[e]);
      }
    }
  };

  loadw(0, wb[0]);
#pragma unroll
  for (int ks = 0; ks < KSTEPS; ++ks) {
    if (ks + 1 < KSTEPS) loadw(ks + 1, wb[(ks + 1) & 1]);
    __builtin_amdgcn_s_setprio(1);
#pragma unroll
    for (int pf = 0; pf < 4; ++pf) {
      const int pt = pf * 16 + ar;
      const int slot = (ks * 4 + q) ^ (pt & 7);
      const bf16x8 a = *(const bf16x8*)(a_base + pt * ROWB + (slot << 4));
      acc[0][pf] = __builtin_amdgcn_mfma_f32_16x16x32_bf16(wb[ks & 1][0], a,
                                                           acc[0][pf], 0, 0, 0);
      acc[1][pf] = __builtin_amdgcn_mfma_f32_16x16x32_bf16(wb[ks & 1][1], a,
                                                           acc[1][pf], 0, 0, 0);
    }
    __builtin_amdgcn_s_setprio(0);
  }
}

// Weight pre-pack (verified R4-R18): [kstep][256][32] tiles, proj columns
// permuted k' = j*8+g (source col = 2 + g*64 + j).
__global__ void cvt_weights(const float* __restrict__ projW,
                            const float* __restrict__ w1,
                            const float* __restrict__ w2,
                            unsigned short* __restrict__ o) {
  const int tot = WSB_ELEMS;
  for (int i = blockIdx.x * blockDim.x + threadIdx.x; i < tot;
       i += gridDim.x * blockDim.x) {
    float v;
    if (i < W1_OFF) {
      const int s = i >> 17, r = i & 131071;
      const int kst = r >> 13, rr = r & 8191;
      const int h = rr >> 5, kw = rr & 31;
      const int kp = kst * 32 + kw;
      const int j = kp >> 3, g = kp & 7;
      v = projW[(s * HID + h) * INF + 2 + g * 64 + j];
    } else if (i < W2_OFF) {
      const int i2 = i - W1_OFF;
      const int w = i2 >> 16, r = i2 & 65535;
      const int kst = r >> 13, h = (r >> 5) & 255, kw = r & 31;
      v = w1[w * 65536 + h * HID + kst * 32 + kw];
    } else {
      const int i2 = i - W2_OFF;
      const int w = i2 >> 16, r = i2 & 65535;
      const int kst = r >> 13, h = (r >> 5) & 255, kw = r & 31;
      v = w2[w * 65536 + h * HID + kst * 32 + kw];
    }
    o[i] = f2bf(v);
  }
}

template<bool WS>
__global__ __launch_bounds__(NTHR, 4)
void fnet_fused(const float* __restrict__ xy,
                const float* __restrict__ w_x,
                const float* __restrict__ w_y,
                const float* __restrict__ proj_W,
                const float* __restrict__ proj_b,
                const float* __restrict__ blk_W1,
                const float* __restrict__ blk_b1,
                const float* __restrict__ blk_W2,
                const float* __restrict__ blk_b2,
                const float* __restrict__ head_W,
                const float* __restrict__ head_b,
                const float* __restrict__ sc_W,
                const unsigned short* __restrict__ wsb,
                float* __restrict__ out) {
  extern __shared__ char smem[];
  char* f_arena = smem;                  // 64 x 1024B swizzled (K=512 bf16)
  char* h_base  = smem;                  // 64 x 512B swizzled (0..32K)
  char* t_base  = smem + T_OFF;          // 64 x 512B swizzled (32K..64K)

  const int tid  = threadIdx.x;
  const int lane = tid & 63;
  const int wave = tid >> 6;           // 0..7
  const int hq   = wave;               // H octant (32 H)
  const int m0   = blockIdx.x * TM;
  const int ar   = lane & 15;
  const int q    = lane >> 4;
  const float hb0 = head_b[0];

  // swizzled h/t tile address for this lane's (hf,pf) uint2 cell
  auto tile_addr = [&](char* base, int hf, int pf) -> char* {
    const int pt = pf * 16 + ar;
    const int slot = (hq * 4 + hf * 2 + (q >> 1)) ^ (pt & 7);
    return base + pt * 512 + (slot << 4) + (q & 1) * 8;
  };

  f32x4 acc[2][4];   // single accumulator, reused by all GEMMs
  auto zacc = [&]() {
#pragma unroll
    for (int a_ = 0; a_ < 2; ++a_)
#pragma unroll
      for (int b_ = 0; b_ < 4; ++b_) acc[a_][b_] = (f32x4)0.f;
  };

  for (int s = 0; s < NSC; ++s) {
    __syncthreads();   // prev-scale LDS reads complete before f restage

    // ---- fourier features -> f arena; shortcut dot -> global atomics ----
    // wave owns 8 pts; lane = freq j (0..63)
    {
      const int fj = lane;
      const float bx = __builtin_amdgcn_exp2f(w_x[s * NFREQ + fj] * LOG2E);
      const float by = __builtin_amdgcn_exp2f(w_y[s * NFREQ + fj] * LOG2E);
      float sc8[8];
#pragma unroll
      for (int g2 = 0; g2 < 8; ++g2) sc8[g2] = sc_W[s * INF + 2 + g2 * NFREQ + fj];
      const float scW0 = sc_W[s * INF], scW1 = sc_W[s * INF + 1];
#pragma unroll 2
      for (int p = 0; p < 8; ++p) {
        const int pt = wave * 8 + p;
        const float x  = xy[(m0 + pt) * 2];
        const float yv = xy[(m0 + pt) * 2 + 1];
        // angle pi*x*B == 2*pi*t revolutions; v_sin/v_cos take revolutions
        float tx = 0.5f * x * bx;  tx -= floorf(tx);
        float ty = 0.5f * yv * by; ty -= floorf(ty);
        const float sx = __builtin_amdgcn_sinf(tx);
        const float cx = __builtin_amdgcn_cosf(tx);
        const float sy = __builtin_amdgcn_sinf(ty);
        const float cy = __builtin_amdgcn_cosf(ty);
        const float p1 = sx * cy, p2 = cx * sy, p3 = cx * cy, p4 = sx * sy;
        const float g0 = sx, g1 = cx, g2 = sy, g3 = cy;
        const float g4 = p1 + p2, g5 = p3 - p4, g6 = p1 - p2, g7 = p3 + p4;
        uint4 wv;
        wv.x = pack2(g0, g1); wv.y = pack2(g2, g3);
        wv.z = pack2(g4, g5); wv.w = pack2(g6, g7);
        *(uint4*)(f_arena + pt * 1024 + ((fj ^ (pt & 7)) << 4)) = wv;
        float psum = g0 * sc8[0] + g1 * sc8[1] + g2 * sc8[2] + g3 * sc8[3]
                   + g4 * sc8[4] + g5 * sc8[5] + g6 * sc8[6] + g7 * sc8[7];
        psum += __shfl_xor(psum, 1, 64);
        psum += __shfl_xor(psum, 2, 64);
        psum += __shfl_xor(psum, 4, 64);
        psum += __shfl_xor(psum, 8, 64);
        psum += __shfl_xor(psum, 16, 64);
        psum += __shfl_xor(psum, 32, 64);
        if (lane == 0)
          atomicAdd(&out[m0 + pt],
                    psum + x * scW0 + yv * scW1 + (s == 0 ? hb0 : 0.f));
      }
    }
    __syncthreads();

    // ---- proj GEMM (K=512): h = gelu((f@W^T + x*w0 + y*w1)*s_in + b) ----
    zacc();
    gemmK<WS, true, 16, 1024>(f_arena, wsb + PROJ_OFF(s),
                              proj_W + s * HID * INF, INF, 2,
                              lane, hq, acc);
    __syncthreads();   // all waves done reading f arena

    // epilogue streamed hf-by-hf, straight to LDS h tile
#pragma unroll
    for (int hf = 0; hf < 2; ++hf) {
      const int Hb = hq * 32 + hf * 16 + 4 * q;
      const float4 pb4 = *(const float4*)(proj_b + s * HID + Hb);
      const float pbv[4] = {pb4.x, pb4.y, pb4.z, pb4.w};
      float wx0[4], wy0[4];
#pragma unroll
      for (int r = 0; r < 4; ++r) {
        const float2 w01 = *(const float2*)(proj_W + (size_t)(s * HID + Hb + r) * INF);
        wx0[r] = w01.x; wy0[r] = w01.y;
      }
#pragma unroll
      for (int pf = 0; pf < 4; ++pf) {
        const int pt = pf * 16 + ar;
        const float2 xp2 = *(const float2*)(xy + (m0 + pt) * 2);
        float hv[4];
#pragma unroll
        for (int r = 0; r < 4; ++r)
          hv[r] = geluf((acc[hf][pf][r] + xp2.x * wx0[r] + xp2.y * wy0[r]) * S_IN + pbv[r]);
        *(uint2*)tile_addr(h_base, hf, pf) =
            make_uint2(pack2(hv[0], hv[1]), pack2(hv[2], hv[3]));
      }
    }
    __syncthreads();

    // ---- residual blocks ----
    for (int b = 0; b < NBLK; ++b) {
      const int wb_ = s * NBLK + b;
      zacc();
      gemmK<WS, false, 8, 512>(h_base, wsb + W1_OFF + wb_ * 65536,
                               blk_W1 + wb_ * 65536, HID, 0,
                               lane, hq, acc);
      // t = gelu(acc*s_h + b1) -> t tile (disjoint from h)
#pragma unroll
      for (int hf = 0; hf < 2; ++hf) {
        const int Hb = hq * 32 + hf * 16 + 4 * q;
        const float4 b14 = *(const float4*)(blk_b1 + wb_ * HID + Hb);
        const float b1v[4] = {b14.x, b14.y, b14.z, b14.w};
#pragma unroll
        for (int pf = 0; pf < 4; ++pf)
          *(uint2*)tile_addr(t_base, hf, pf) =
              make_uint2(pack2(geluf(acc[hf][pf][0] * S_H + b1v[0]),
                               geluf(acc[hf][pf][1] * S_H + b1v[1])),
                         pack2(geluf(acc[hf][pf][2] * S_H + b1v[2]),
                               geluf(acc[hf][pf][3] * S_H + b1v[3])));
      }
      __syncthreads();   // t complete; all GEMM1 h-reads done

      zacc();
      gemmK<WS, false, 8, 512>(t_base, wsb + W2_OFF + wb_ * 65536,
                               blk_W2 + wb_ * 65536, HID, 0,
                               lane, hq, acc);

      if (b + 1 < NBLK) {
        // h' = h(LDS readback, own cells) + acc*s_h + b2 -> h tile
#pragma unroll
        for (int hf = 0; hf < 2; ++hf) {
          const int Hb = hq * 32 + hf * 16 + 4 * q;
          const float4 b24 = *(const float4*)(blk_b2 + wb_ * HID + Hb);
          const float b2v[4] = {b24.x, b24.y, b24.z, b24.w};
#pragma unroll
          for (int pf = 0; pf < 4; ++pf) {
            const uint2 u = *(const uint2*)tile_addr(h_base, hf, pf);
            float hv[4];
            hv[0] = __uint_as_float(u.x << 16)         + acc[hf][pf][0] * S_H + b2v[0];
            hv[1] = __uint_as_float(u.x & 0xffff0000u) + acc[hf][pf][1] * S_H + b2v[1];
            hv[2] = __uint_as_float(u.y << 16)         + acc[hf][pf][2] * S_H + b2v[2];
            hv[3] = __uint_as_float(u.y & 0xffff0000u) + acc[hf][pf][3] * S_H + b2v[3];
            *(uint2*)tile_addr(h_base, hf, pf) =
                make_uint2(pack2(hv[0], hv[1]), pack2(hv[2], hv[3]));
          }
        }
      } else {
        // final head partial: hf-outer so b2/head_W load once per hf
        float v[4] = {0.f, 0.f, 0.f, 0.f};
#pragma unroll
        for (int hf = 0; hf < 2; ++hf) {
          const int Hb = hq * 32 + hf * 16 + 4 * q;
          const float4 b24 = *(const float4*)(blk_b2 + wb_ * HID + Hb);
          const float4 hw4 = *(const float4*)(head_W + Hb);
#pragma unroll
          for (int pf = 0; pf < 4; ++pf) {
            const uint2 u = *(const uint2*)tile_addr(h_base, hf, pf);
            v[pf] += (__uint_as_float(u.x << 16)         + acc[hf][pf][0] * S_H + b24.x) * hw4.x
                   + (__uint_as_float(u.x & 0xffff0000u) + acc[hf][pf][1] * S_H + b24.y) * hw4.y
                   + (__uint_as_float(u.y << 16)         + acc[hf][pf][2] * S_H + b24.z) * hw4.z
                   + (__uint_as_float(u.y & 0xffff0000u) + acc[hf][pf][3] * S_H + b24.w) * hw4.w;
          }
        }
#pragma unroll
        for (int pf = 0; pf < 4; ++pf) {
          float vv = v[pf];
          vv += __shfl_xor(vv, 16, 64);
          vv += __shfl_xor(vv, 32, 64);
          if (lane < 16) atomicAdd(&out[m0 + pf * 16 + ar], vv);
        }
      }
      __syncthreads();
    }
  }
}

extern "C" void kernel_launch(void* const* d_in, const int* in_sizes, int n_in,
                              void* d_out, int out_size, void* d_ws, size_t ws_size,
                              hipStream_t stream) {
  (void)in_sizes; (void)n_in;
  const float* xy     = (const float*)d_in[0];
  const float* w_x    = (const float*)d_in[1];
  const float* w_y    = (const float*)d_in[2];
  const float* proj_W = (const float*)d_in[3];
  const float* proj_b = (const float*)d_in[4];
  const float* blk_W1 = (const float*)d_in[5];
  const float* blk_b1 = (const float*)d_in[6];
  const float* blk_W2 = (const float*)d_in[7];
  const float* blk_b2 = (const float*)d_in[8];
  const float* head_W = (const float*)d_in[9];
  const float* head_b = (const float*)d_in[10];
  const float* sc_W   = (const float*)d_in[11];
  float* out = (float*)d_out;

  const bool use_ws = ws_size >= (size_t)WSB_ELEMS * 2;
  const int nblocks = out_size / TM;   // 65536/64 = 1024

  (void)hipMemsetAsync(d_out, 0, (size_t)out_size * sizeof(float), stream);

  if (use_ws) {
    cvt_weights<<<768, 256, 0, stream>>>(proj_W, blk_W1, blk_W2,
                                         (unsigned short*)d_ws);
    fnet_fused<true><<<nblocks, NTHR, SMEM_BYTES, stream>>>(
        xy, w_x, w_y, proj_W, proj_b, blk_W1, blk_b1, blk_W2, blk_b2,
        head_W, head_b, sc_W, (const unsigned short*)d_ws, out);
  } else {
    fnet_fused<false><<<nblocks, NTHR, SMEM_BYTES, stream>>>(
        xy, w_x, w_y, proj_W, proj_b, blk_W1, blk_b1, blk_W2, blk_b2,
        head_W, head_b, sc_W, (const unsigned short*)nullptr, out);
  }
}